// Round 4
// baseline (1311.442 us; speedup 1.0000x reference)
//
#include <hip/hip_runtime.h>

// ---------------------------------------------------------------------------
// SparsePoolingLayer: u0 = conv5x5_valid(x, W_ff); iterate
//   u <- 0.5*u + 0.5*(u0 - W_rec @ a); a = relu(u - thr)
// until ||u_new - u||/||u_new|| < 1e-3 (device-checked), max 41 iterations.
//
// R12 design: C-fragment-layout register update.
//  - R11 post-mortem: conv LDC 42 (84 B rows) broke 16-B granule alignment
//    of b128 LDS ops -> conflicts UP (2.3e7->3.5e7), conv 161->210 us.
//    REVERTED to LDC 40. Iter improved ~250 us from 8-wave blocks.
//  - R12: u-update performed directly in MFMA C-layout registers:
//    acc[i][j][d] = rec at (n=j*16+r, oc=w*32+i*16+q*4+d). sv/u0 are loaded
//    as uint2 at those coords; update+norms in regs (rec stays fp32 --
//    strictly closer to reference than the old fp16 LDS round-trip);
//    uA/uB stored as uint2 directly. Removes P3 LDS write + P4 LDS read,
//    6 barriers -> 3 per pair. aA is recomputed from rounded sv after the
//    barrier (cheap) instead of held -> peak regs ~100 < 128 cap, no spill.
//  - Pair semantics unchanged: writes u_A (odd it) and u_B (even it);
//    sel_kernel picks first-crossing buffer.
// ---------------------------------------------------------------------------

typedef __attribute__((ext_vector_type(8))) short short8;
typedef __attribute__((ext_vector_type(4))) float f32x4;

#define NTOT 115200   // 32*60*60
#define CHW  262144   // 64*64*64
#define HW2  4096     // 64*64
#define LDA  264      // a_lds row stride in shorts (528 B)
#define LDC  40       // conv LDS row stride in shorts (80 B, 16B-aligned rows)

__device__ __forceinline__ unsigned short f2bf(float f) {
  unsigned int u = __float_as_uint(f);
  unsigned int r = u + 0x7FFFu + ((u >> 16) & 1u);
  return (unsigned short)(r >> 16);
}
__device__ __forceinline__ float bf2f(unsigned short h) {
  return __uint_as_float(((unsigned int)h) << 16);
}
__device__ __forceinline__ unsigned short f2h(float f) {
  _Float16 x = (_Float16)f;
  unsigned short r;
  __builtin_memcpy(&r, &x, 2);
  return r;
}
__device__ __forceinline__ float h2f(unsigned short h) {
  _Float16 x;
  __builtin_memcpy(&x, &h, 2);
  return (float)x;
}

// ---------------------------------------------------------------------------
// Weight prep:
//  wff[o][(ky*5+kx)*64+ci] bf16  (conv A operand rows)
//  wrec_sw: per-lane MFMA fragment order: for 8-wide ic-chunk cc (0..31),
//  oc row o: wrec_sw[((cc*256)+o)*8 + j] = W_rec[o][cc*8+j]
__global__ void cast_weights(const float* __restrict__ wff_f,
                             const float* __restrict__ wrec_f,
                             unsigned short* __restrict__ wff,
                             unsigned short* __restrict__ wrec_sw) {
  int tid = blockIdx.x * 256 + threadIdx.x;
  if (tid < 409600) {
    int o = tid / 1600, k = tid % 1600;
    int kk = k >> 6, ci = k & 63;            // k = kk*64 + ci
    wff[tid] = f2bf(wff_f[o * 1600 + ci * 25 + kk]);
  } else if (tid < 409600 + 65536) {
    int i = tid - 409600;
    int o = i >> 8, ic = i & 255;
    wrec_sw[(((ic >> 3) << 8) + o) * 8 + (ic & 7)] = f2bf(wrec_f[i]);
  }
}

// ---------------------------------------------------------------------------
// x NCHW fp32 -> NHWC bf16: xt[(b*4096 + y*64 + x)*64 + ci].
__global__ __launch_bounds__(256) void transpose_x(
    const float* __restrict__ x, unsigned short* __restrict__ xt) {
  int g = blockIdx.x * 256 + threadIdx.x;          // 131072 = 32*4096
  const float* src = x + (long)(g >> 12) * CHW + (g & 4095);
  unsigned short* dst = xt + (long)g * 64;
#pragma unroll
  for (int oct = 0; oct < 8; ++oct) {
    alignas(16) unsigned short tmp[8];
#pragma unroll
    for (int d = 0; d < 8; ++d)
      tmp[d] = f2bf(src[(oct * 8 + d) * HW2]);
    *(int4*)(dst + oct * 8) = *(const int4*)tmp;
  }
}

// ---------------------------------------------------------------------------
// Conv as implicit GEMM, D[oc][n] (A = wff, B = x). Block 128oc x 128n,
// BK=32, grid (900, 2). Writes u0 fp16 [n][oc] as uint2 (4 oc per lane).
__global__ __launch_bounds__(256) void conv_kernel(
    const unsigned short* __restrict__ xt,
    const unsigned short* __restrict__ wff,
    unsigned short* __restrict__ u0_nc) {
  __shared__ short As[128 * LDC];  // x-tile  [n][k]  pad 32->40
  __shared__ short Bs[128 * LDC];  // wff     [oc][k]
  const int t = threadIdx.x;
  const int n0 = blockIdx.x * 128;
  const int oc0 = blockIdx.y * 128;
  const int lane = t & 63, w = t >> 6;
  const int q = lane >> 4, r = lane & 15;
  const int woc = w >> 1, wn = w & 1;      // oc-half, n-half
  const int qt = t & 3, mrow = t >> 2;     // staging: row mrow(+64), 16B qt

  int xbase[2];
#pragma unroll
  for (int p = 0; p < 2; ++p) {
    int n = n0 + p * 64 + mrow;
    int bb = n / 3600, rem = n - bb * 3600;
    int yy = rem / 60, xx = rem - yy * 60;
    xbase[p] = (bb * 4096 + yy * 64 + xx) * 64 + qt * 8;
  }

  f32x4 acc[4][4];
#pragma unroll
  for (int i = 0; i < 4; i++)
#pragma unroll
    for (int j = 0; j < 4; j++) acc[i][j] = (f32x4){0.f, 0.f, 0.f, 0.f};

  for (int c = 0; c < 50; ++c) {
    const int k0 = c * 32;
    const int kk = c >> 1;                 // ky*5+kx, uniform per chunk
    const int ky = kk / 5, kx = kk - ky * 5;
    const int choff = (ky * 64 + kx) * 64 + (c & 1) * 32;  // scalar-uniform

    __syncthreads();
#pragma unroll
    for (int p = 0; p < 2; ++p) {          // wff: 128 oc-rows x 32 k
      int m = p * 64 + mrow;
      *(int4*)(&Bs[m * LDC + qt * 8]) =
          *(const int4*)(wff + (oc0 + m) * 1600 + k0 + qt * 8);
    }
#pragma unroll
    for (int p = 0; p < 2; ++p) {          // x-tile: contiguous bf16 (NHWC)
      int m = p * 64 + mrow;
      *(int4*)(&As[m * LDC + qt * 8]) = *(const int4*)(xt + xbase[p] + choff);
    }
    __syncthreads();

    short8 xf[4], wf[4];
#pragma unroll
    for (int j = 0; j < 4; j++)
      xf[j] = *(const short8*)(&As[(wn * 64 + j * 16 + r) * LDC + q * 8]);
#pragma unroll
    for (int i = 0; i < 4; i++)
      wf[i] = *(const short8*)(&Bs[(woc * 64 + i * 16 + r) * LDC + q * 8]);
#pragma unroll
    for (int i = 0; i < 4; i++)
#pragma unroll
      for (int j = 0; j < 4; j++)
        acc[i][j] = __builtin_amdgcn_mfma_f32_16x16x32_bf16(wf[i], xf[j],
                                                            acc[i][j], 0, 0, 0);
  }

  // epilogue: lane holds 4 consecutive oc (d) at fixed n -> uint2 stores
#pragma unroll
  for (int j = 0; j < 4; j++) {
    const int n = n0 + wn * 64 + j * 16 + r;
#pragma unroll
    for (int i = 0; i < 4; i++) {
      const int oc = oc0 + woc * 64 + i * 16 + q * 4;
      alignas(8) unsigned short up[4];
#pragma unroll
      for (int d = 0; d < 4; ++d) up[d] = f2h(acc[i][j][d]);   // fp16 u0
      *(uint2*)(&u0_nc[n * 256 + oc]) = *(const uint2*)up;
    }
  }
}

// ---------------------------------------------------------------------------
// 8-wave GEMM accumulate: acc = W_rec @ a, C-layout. Wave w owns oc rows
// [32w, 32w+32). No LDS writeback, no barriers (caller manages).
__device__ __forceinline__ void gemm_acc8(const short* a_lds,
                                          const unsigned short* __restrict__
                                              wrec_sw,
                                          int w, int q, int r,
                                          f32x4 acc[2][4]) {
#pragma unroll
  for (int i = 0; i < 2; i++)
#pragma unroll
    for (int j = 0; j < 4; j++) acc[i][j] = (f32x4){0.f, 0.f, 0.f, 0.f};

#pragma unroll
  for (int c = 0; c < 8; ++c) {
    short8 afr[2], bfr[4];
#pragma unroll
    for (int i = 0; i < 2; i++)
      afr[i] = *(const short8*)(wrec_sw +
               (((c * 4 + q) << 8) + w * 32 + i * 16 + r) * 8);
#pragma unroll
    for (int j = 0; j < 4; j++)
      bfr[j] = *(const short8*)(&a_lds[(j * 16 + r) * LDA + c * 32 + q * 8]);
#pragma unroll
    for (int i = 0; i < 2; i++)
#pragma unroll
      for (int j = 0; j < 4; j++)
        acc[i][j] = __builtin_amdgcn_mfma_f32_16x16x32_bf16(afr[i], bfr[j],
                                                            acc[i][j], 0, 0, 0);
  }
}

// ---------------------------------------------------------------------------
// Paired iteration, 512 threads / 8 waves, grid 1800 (64 n each), C-layout.
// Element coords for lane (w,q,r), regs (i,j,d):
//   n = n0 + j*16 + r, oc = w*32 + i*16 + q*4 + d.
// sv/u0c: uint2-packed fp16 (16 VGPRs each). rec stays fp32 in acc.
template <int FIRST>
__global__ __launch_bounds__(512, 4) void iter_pair(
    const unsigned short* __restrict__ wrec_sw,
    const unsigned short* __restrict__ u0, const float* __restrict__ thr,
    const unsigned short* __restrict__ uin,      // prev even state (uB)
    unsigned short* __restrict__ uA, unsigned short* __restrict__ uB,
    float* __restrict__ norms, int* __restrict__ flag, int itA) {
  __shared__ short a_lds[64 * LDA];
  __shared__ float red[32];

  const int t = threadIdx.x;
  if (!FIRST) {
    if (*(volatile int*)flag) return;            // converged earlier
    float dA = 0.f, nA = 0.f, dB = 0.f, nB = 0.f;
#pragma unroll
    for (int s = 0; s < 8; ++s) {
      dA += norms[(itA - 2) * 16 + s];
      nA += norms[(itA - 2) * 16 + 8 + s];
      dB += norms[(itA - 1) * 16 + s];
      nB += norms[(itA - 1) * 16 + 8 + s];
    }
    if (dA < 1e-6f * nA || dB < 1e-6f * nB) {    // fro ratio < 1e-3
      if (t == 0) *flag = 1;
      return;
    }
  }

  const int n0 = blockIdx.x * 64;
  const int lane = t & 63, w = t >> 6;     // w in 0..7
  const int q = lane >> 4, r = lane & 15;
  const int ob = (n0 + r) * 256 + w * 32 + q * 4;   // + j*4096 + i*16

  float thc[2][4];
#pragma unroll
  for (int i = 0; i < 2; ++i) {
    float4 th = *(const float4*)(thr + w * 32 + i * 16 + q * 4);
    thc[i][0] = th.x; thc[i][1] = th.y; thc[i][2] = th.z; thc[i][3] = th.w;
  }

  uint2 sv[2][4], u0c[2][4];
#pragma unroll
  for (int j = 0; j < 4; ++j)
#pragma unroll
    for (int i = 0; i < 2; ++i) {
      const int off = ob + j * 4096 + i * 16;
      u0c[i][j] = *(const uint2*)(u0 + off);
      sv[i][j] = FIRST ? u0c[i][j] : *(const uint2*)(uin + off);
    }

  // ---- a0 = relu(sv - thr) -> LDS ----
#pragma unroll
  for (int j = 0; j < 4; ++j)
#pragma unroll
    for (int i = 0; i < 2; ++i) {
      const unsigned short* hs = (const unsigned short*)&sv[i][j];
      alignas(8) unsigned short ap[4];
#pragma unroll
      for (int d = 0; d < 4; ++d) {
        float a = h2f(hs[d]) - thc[i][d];
        ap[d] = f2bf(a > 0.f ? a : 0.f);
      }
      *(uint2*)(&a_lds[(j * 16 + r) * LDA + w * 32 + i * 16 + q * 4]) =
          *(const uint2*)ap;
    }
  __syncthreads();

  // ---- iteration A: GEMM + in-register update ----
  f32x4 acc[2][4];
  gemm_acc8(a_lds, wrec_sw, w, q, r, acc);

  float d2A = 0.f, n2A = 0.f;
#pragma unroll
  for (int j = 0; j < 4; ++j)
#pragma unroll
    for (int i = 0; i < 2; ++i) {
      const unsigned short* us = (const unsigned short*)&u0c[i][j];
      const unsigned short* hs = (const unsigned short*)&sv[i][j];
      alignas(8) unsigned short up[4];
#pragma unroll
      for (int d = 0; d < 4; ++d) {
        float uo = FIRST ? 0.f : h2f(hs[d]);
        float un = 0.5f * uo + 0.5f * (h2f(us[d]) - acc[i][j][d]);
        float df = un - uo;
        d2A += df * df;
        n2A += un * un;
        up[d] = f2h(un);
      }
      sv[i][j] = *(const uint2*)up;
      *(uint2*)(uA + ob + j * 4096 + i * 16) = sv[i][j];  // hides under GEMM B
    }
  __syncthreads();                         // all GEMM-A a_lds reads complete

  // ---- aA = relu(sv - thr) -> LDS (recomputed from rounded sv) ----
#pragma unroll
  for (int j = 0; j < 4; ++j)
#pragma unroll
    for (int i = 0; i < 2; ++i) {
      const unsigned short* hs = (const unsigned short*)&sv[i][j];
      alignas(8) unsigned short ap[4];
#pragma unroll
      for (int d = 0; d < 4; ++d) {
        float a = h2f(hs[d]) - thc[i][d];
        ap[d] = f2bf(a > 0.f ? a : 0.f);
      }
      *(uint2*)(&a_lds[(j * 16 + r) * LDA + w * 32 + i * 16 + q * 4]) =
          *(const uint2*)ap;
    }
  __syncthreads();

  // ---- iteration B: GEMM + in-register update ----
  gemm_acc8(a_lds, wrec_sw, w, q, r, acc);

  float d2B = 0.f, n2B = 0.f;
#pragma unroll
  for (int j = 0; j < 4; ++j)
#pragma unroll
    for (int i = 0; i < 2; ++i) {
      const unsigned short* us = (const unsigned short*)&u0c[i][j];
      const unsigned short* hs = (const unsigned short*)&sv[i][j];
      alignas(8) unsigned short up[4];
#pragma unroll
      for (int d = 0; d < 4; ++d) {
        float uo = h2f(hs[d]);
        float un = 0.5f * uo + 0.5f * (h2f(us[d]) - acc[i][j][d]);
        float df = un - uo;
        d2B += df * df;
        n2B += un * un;
        up[d] = f2h(un);
      }
      *(uint2*)(uB + ob + j * 4096 + i * 16) = *(const uint2*)up;
    }

  // ---- reduction: wave -> block -> 8-slot atomics ----
#pragma unroll
  for (int off = 32; off; off >>= 1) {
    d2A += __shfl_down(d2A, off, 64);
    n2A += __shfl_down(n2A, off, 64);
    d2B += __shfl_down(d2B, off, 64);
    n2B += __shfl_down(n2B, off, 64);
  }
  if (lane == 0) {
    red[w] = d2A; red[8 + w] = n2A; red[16 + w] = d2B; red[24 + w] = n2B;
  }
  __syncthreads();
  if (t == 0) {
    float a0 = 0.f, a1 = 0.f, a2 = 0.f, a3 = 0.f;
#pragma unroll
    for (int s = 0; s < 8; ++s) {
      a0 += red[s]; a1 += red[8 + s]; a2 += red[16 + s]; a3 += red[24 + s];
    }
    const int slot = blockIdx.x & 7;
    atomicAdd(&norms[itA * 16 + slot], a0);
    atomicAdd(&norms[itA * 16 + 8 + slot], a1);
    atomicAdd(&norms[(itA + 1) * 16 + slot], a2);
    atomicAdd(&norms[(itA + 1) * 16 + 8 + slot], a3);
  }
}

// ---------------------------------------------------------------------------
// Single iteration it: uin -> uout, C-layout (512 threads / 8 waves). Used
// for it=41 (pair path) and the fallback chain.
template <int FIRST>
__global__ __launch_bounds__(512, 4) void iter_one(
    const unsigned short* __restrict__ wrec_sw,
    const unsigned short* __restrict__ u0, const float* __restrict__ thr,
    const unsigned short* __restrict__ uin, unsigned short* __restrict__ uout,
    float* __restrict__ norms, int* __restrict__ flag, int it) {
  __shared__ short a_lds[64 * LDA];
  __shared__ float red[16];

  const int t = threadIdx.x;
  if (!FIRST) {
    if (*(volatile int*)flag) return;
    float dA = 0.f, nA = 0.f, dB = 0.f, nB = 0.f;
#pragma unroll
    for (int s = 0; s < 8; ++s) {
      dA += norms[(it - 2) * 16 + s];
      nA += norms[(it - 2) * 16 + 8 + s];
      dB += norms[(it - 1) * 16 + s];
      nB += norms[(it - 1) * 16 + 8 + s];
    }
    if (dA < 1e-6f * nA || dB < 1e-6f * nB) {
      if (t == 0) *flag = 1;
      return;
    }
  }

  const int n0 = blockIdx.x * 64;
  const int lane = t & 63, w = t >> 6;
  const int q = lane >> 4, r = lane & 15;
  const int ob = (n0 + r) * 256 + w * 32 + q * 4;

  float thc[2][4];
#pragma unroll
  for (int i = 0; i < 2; ++i) {
    float4 th = *(const float4*)(thr + w * 32 + i * 16 + q * 4);
    thc[i][0] = th.x; thc[i][1] = th.y; thc[i][2] = th.z; thc[i][3] = th.w;
  }

  uint2 sv[2][4], u0c[2][4];
#pragma unroll
  for (int j = 0; j < 4; ++j)
#pragma unroll
    for (int i = 0; i < 2; ++i) {
      const int off = ob + j * 4096 + i * 16;
      u0c[i][j] = *(const uint2*)(u0 + off);
      sv[i][j] = FIRST ? u0c[i][j] : *(const uint2*)(uin + off);
    }

#pragma unroll
  for (int j = 0; j < 4; ++j)
#pragma unroll
    for (int i = 0; i < 2; ++i) {
      const unsigned short* hs = (const unsigned short*)&sv[i][j];
      alignas(8) unsigned short ap[4];
#pragma unroll
      for (int d = 0; d < 4; ++d) {
        float a = h2f(hs[d]) - thc[i][d];
        ap[d] = f2bf(a > 0.f ? a : 0.f);
      }
      *(uint2*)(&a_lds[(j * 16 + r) * LDA + w * 32 + i * 16 + q * 4]) =
          *(const uint2*)ap;
    }
  __syncthreads();

  f32x4 acc[2][4];
  gemm_acc8(a_lds, wrec_sw, w, q, r, acc);

  float d2 = 0.f, n2 = 0.f;
#pragma unroll
  for (int j = 0; j < 4; ++j)
#pragma unroll
    for (int i = 0; i < 2; ++i) {
      const unsigned short* us = (const unsigned short*)&u0c[i][j];
      const unsigned short* hs = (const unsigned short*)&sv[i][j];
      alignas(8) unsigned short up[4];
#pragma unroll
      for (int d = 0; d < 4; ++d) {
        float uo = FIRST ? 0.f : h2f(hs[d]);
        float un = 0.5f * uo + 0.5f * (h2f(us[d]) - acc[i][j][d]);
        float df = un - uo;
        d2 += df * df;
        n2 += un * un;
        up[d] = f2h(un);
      }
      *(uint2*)(uout + ob + j * 4096 + i * 16) = *(const uint2*)up;
    }

#pragma unroll
  for (int off = 32; off; off >>= 1) {
    d2 += __shfl_down(d2, off, 64);
    n2 += __shfl_down(n2, off, 64);
  }
  if (lane == 0) { red[w] = d2; red[8 + w] = n2; }
  __syncthreads();
  if (t == 0) {
    float a0 = 0.f, a1 = 0.f;
#pragma unroll
    for (int s = 0; s < 8; ++s) { a0 += red[s]; a1 += red[8 + s]; }
    const int slot = blockIdx.x & 7;
    atomicAdd(&norms[it * 16 + slot], a0);
    atomicAdd(&norms[it * 16 + 8 + slot], a1);
  }
}

// ---------------------------------------------------------------------------
// sel: first it in [1,41] with d2 < 1e-6*n2 (else 41); odd -> uA (sel=0),
// even -> uB (sel=1).
__global__ void sel_kernel(const float* __restrict__ norms,
                           int* __restrict__ sel) {
  int it = 1;
  for (; it <= 41; ++it) {
    float d = 0.f, n = 0.f;
    for (int s = 0; s < 8; ++s) {
      d += norms[it * 16 + s];
      n += norms[it * 16 + 8 + s];
    }
    if (d < 1e-6f * n) break;
  }
  if (it > 41) it = 41;
  *sel = (it & 1) ? 0 : 1;
}
__global__ void set_sel(int* __restrict__ sel, int v) { *sel = v; }

// ---------------------------------------------------------------------------
// Final: out(NCHW fp32) = relu(u - thr), u fp16 [n][oc], buffer chosen by sel.
__global__ __launch_bounds__(256) void final_out(
    const unsigned short* __restrict__ uA,
    const unsigned short* __restrict__ uB, const int* __restrict__ sel,
    const float* __restrict__ thr, float* __restrict__ out) {
  const unsigned short* u = (*sel) ? uB : uA;
  const int t = threadIdx.x, lane = t & 63, w = t >> 6;
  const int n = blockIdx.x * 64 + lane;
  const int b = n / 3600, s = n - b * 3600;
  float* ob = out + (long)b * 921600 + s;
  const unsigned short* ub = u + (long)n * 256 + w * 64;
#pragma unroll
  for (int g = 0; g < 8; ++g) {            // 8 groups x 8 fp16 = 64 oc
    int4 raw = *(const int4*)(ub + g * 8);
    const unsigned short* rs = (const unsigned short*)&raw;
#pragma unroll
    for (int d = 0; d < 8; ++d) {
      int oc = w * 64 + g * 8 + d;
      float v = h2f(rs[d]) - thr[oc];
      ob[oc * 3600] = v > 0.f ? v : 0.f;
    }
  }
}

// ---------------------------------------------------------------------------
extern "C" void kernel_launch(void* const* d_in, const int* in_sizes, int n_in,
                              void* d_out, int out_size, void* d_ws,
                              size_t ws_size, hipStream_t stream) {
  const float* x      = (const float*)d_in[0];
  const float* wff_f  = (const float*)d_in[1];
  const float* wrec_f = (const float*)d_in[2];
  const float* thr    = (const float*)d_in[3];
  float* out = (float*)d_out;

  char* ws = (char*)d_ws;
  int* flag = (int*)ws;                                      // [0,4)
  int* sel  = (int*)(ws + 8);                                // [8,12)
  float* norms = (float*)(ws + 64);                          // 42*16*4 = 2688 B
  unsigned short* wff     = (unsigned short*)(ws + 4096);      // 819200 B
  unsigned short* wrec_sw = (unsigned short*)(ws + 823296);    // 131072 B
  // xt (16.8 MB) aliases the head of uB (59 MB): xt dies after conv; uB is
  // first written in iteration B of the first pair launch.
  unsigned short* xt = (unsigned short*)(ws + 983040);
  unsigned short* uB = (unsigned short*)(ws + 983040);         // 58982400 B
  unsigned short* u0 = (unsigned short*)(ws + 59965440);       // 58982400 B
  unsigned short* uA = (unsigned short*)(ws + 118947840);      // 58982400 B
  const size_t NEEDED = 118947840ULL + 58982400ULL;            // ~178 MB

  hipMemsetAsync(d_ws, 0, 4096, stream);  // flag + sel + norm slots
  cast_weights<<<1856, 256, 0, stream>>>(wff_f, wrec_f, wff, wrec_sw);
  transpose_x<<<512, 256, 0, stream>>>(x, xt);
  conv_kernel<<<dim3(900, 2), 256, 0, stream>>>(xt, wff, u0);

  if (ws_size >= NEEDED) {
    // paired path: (1,2), (3,4), ..., (39,40), then single 41 -> 41 bodies
    iter_pair<1><<<1800, 512, 0, stream>>>(wrec_sw, u0, thr, uB, uA, uB,
                                           norms, flag, 1);
    for (int itA = 3; itA <= 39; itA += 2)
      iter_pair<0><<<1800, 512, 0, stream>>>(wrec_sw, u0, thr, uB, uA, uB,
                                             norms, flag, itA);
    iter_one<0><<<1800, 512, 0, stream>>>(wrec_sw, u0, thr, uB, uA, norms,
                                          flag, 41);
    sel_kernel<<<1, 1, 0, stream>>>(norms, sel);
  } else {
    // fallback: proven single-step chain in uB
    iter_one<1><<<1800, 512, 0, stream>>>(wrec_sw, u0, thr, uB, uB, norms,
                                          flag, 1);
    for (int it = 2; it <= 41; ++it)
      iter_one<0><<<1800, 512, 0, stream>>>(wrec_sw, u0, thr, uB, uB, norms,
                                            flag, it);
    set_sel<<<1, 1, 0, stream>>>(sel, 1);
  }
  final_out<<<1800, 256, 0, stream>>>(uA, uB, sel, thr, out);
}

// Round 5
// 1075.761 us; speedup vs baseline: 1.2191x; 1.2191x over previous
//
#include <hip/hip_runtime.h>

// ---------------------------------------------------------------------------
// SparsePoolingLayer: u0 = conv5x5_valid(x, W_ff); iterate
//   u <- 0.5*u + 0.5*(u0 - W_rec @ a); a = relu(u - thr)
// until ||u_new - u||/||u_new|| < 1e-3 (device-checked), max 41 iterations.
//
// R13 design: fragment-linear (FL) u layout.
//  - R12 post-mortem: C-layout direct global I/O = 8-B uint2 at 512-B lane
//    stride -> L2 partial-line thrash: pair FETCH 204 MB / WRITE 358 MB vs
//    118/118 expected -> 170 us traffic-bound. R11's LDS round-trip was the
//    implicit layout converter.
//  - R13: u0/uA/uB stored in FL order addr(n,oc) = tile*16384 + j*4096 +
//    t*8 + i*4 + d, where tile=n>>6, j=(n>>4)&3, t=(oc>>5)*64+((oc>>2)&3)*16
//    +(n&15), i=(oc>>4)&1, d=oc&3. Iter thread t accesses int4 at
//    base + j*4096: perfectly coalesced (1 KB/wave-instr), constant-offset
//    addressing. Conv epilogue writes FL (also coalesced); final_out reads
//    FL and scatters to NCHW.
//  - Compute structure from R12 kept: GEMM accumulates in C-layout regs,
//    update+norms in regs, rec stays fp32, a regenerated into LDS.
// ---------------------------------------------------------------------------

typedef __attribute__((ext_vector_type(8))) short short8;
typedef __attribute__((ext_vector_type(4))) float f32x4;

#define NTOT 115200   // 32*60*60
#define CHW  262144   // 64*64*64
#define HW2  4096     // 64*64
#define LDA  264      // a_lds row stride in shorts (528 B)
#define LDC  40       // conv LDS row stride in shorts (80 B, 16B-aligned rows)

__device__ __forceinline__ unsigned short f2bf(float f) {
  unsigned int u = __float_as_uint(f);
  unsigned int r = u + 0x7FFFu + ((u >> 16) & 1u);
  return (unsigned short)(r >> 16);
}
__device__ __forceinline__ float bf2f(unsigned short h) {
  return __uint_as_float(((unsigned int)h) << 16);
}
__device__ __forceinline__ unsigned short f2h(float f) {
  _Float16 x = (_Float16)f;
  unsigned short r;
  __builtin_memcpy(&r, &x, 2);
  return r;
}
__device__ __forceinline__ float h2f(unsigned short h) {
  _Float16 x;
  __builtin_memcpy(&x, &h, 2);
  return (float)x;
}

// ---------------------------------------------------------------------------
// Weight prep:
//  wff[o][(ky*5+kx)*64+ci] bf16  (conv A operand rows)
//  wrec_sw: per-lane MFMA fragment order: for 8-wide ic-chunk cc (0..31),
//  oc row o: wrec_sw[((cc*256)+o)*8 + j] = W_rec[o][cc*8+j]
__global__ void cast_weights(const float* __restrict__ wff_f,
                             const float* __restrict__ wrec_f,
                             unsigned short* __restrict__ wff,
                             unsigned short* __restrict__ wrec_sw) {
  int tid = blockIdx.x * 256 + threadIdx.x;
  if (tid < 409600) {
    int o = tid / 1600, k = tid % 1600;
    int kk = k >> 6, ci = k & 63;            // k = kk*64 + ci
    wff[tid] = f2bf(wff_f[o * 1600 + ci * 25 + kk]);
  } else if (tid < 409600 + 65536) {
    int i = tid - 409600;
    int o = i >> 8, ic = i & 255;
    wrec_sw[(((ic >> 3) << 8) + o) * 8 + (ic & 7)] = f2bf(wrec_f[i]);
  }
}

// ---------------------------------------------------------------------------
// x NCHW fp32 -> NHWC bf16: xt[(b*4096 + y*64 + x)*64 + ci].
__global__ __launch_bounds__(256) void transpose_x(
    const float* __restrict__ x, unsigned short* __restrict__ xt) {
  int g = blockIdx.x * 256 + threadIdx.x;          // 131072 = 32*4096
  const float* src = x + (long)(g >> 12) * CHW + (g & 4095);
  unsigned short* dst = xt + (long)g * 64;
#pragma unroll
  for (int oct = 0; oct < 8; ++oct) {
    alignas(16) unsigned short tmp[8];
#pragma unroll
    for (int d = 0; d < 8; ++d)
      tmp[d] = f2bf(src[(oct * 8 + d) * HW2]);
    *(int4*)(dst + oct * 8) = *(const int4*)tmp;
  }
}

// ---------------------------------------------------------------------------
// Conv as implicit GEMM, D[oc][n] (A = wff, B = x). Block 128oc x 128n,
// BK=32, grid (900, 2). Writes u0 fp16 in FL layout (coalesced int4).
__global__ __launch_bounds__(256) void conv_kernel(
    const unsigned short* __restrict__ xt,
    const unsigned short* __restrict__ wff,
    unsigned short* __restrict__ u0_fl) {
  __shared__ short As[128 * LDC];  // x-tile  [n][k]  pad 32->40
  __shared__ short Bs[128 * LDC];  // wff     [oc][k]
  const int t = threadIdx.x;
  const int n0 = blockIdx.x * 128;
  const int oc0 = blockIdx.y * 128;
  const int lane = t & 63, w = t >> 6;
  const int q = lane >> 4, r = lane & 15;
  const int woc = w >> 1, wn = w & 1;      // oc-half, n-half
  const int qt = t & 3, mrow = t >> 2;     // staging: row mrow(+64), 16B qt

  int xbase[2];
#pragma unroll
  for (int p = 0; p < 2; ++p) {
    int n = n0 + p * 64 + mrow;
    int bb = n / 3600, rem = n - bb * 3600;
    int yy = rem / 60, xx = rem - yy * 60;
    xbase[p] = (bb * 4096 + yy * 64 + xx) * 64 + qt * 8;
  }

  f32x4 acc[4][4];
#pragma unroll
  for (int i = 0; i < 4; i++)
#pragma unroll
    for (int j = 0; j < 4; j++) acc[i][j] = (f32x4){0.f, 0.f, 0.f, 0.f};

  for (int c = 0; c < 50; ++c) {
    const int k0 = c * 32;
    const int kk = c >> 1;                 // ky*5+kx, uniform per chunk
    const int ky = kk / 5, kx = kk - ky * 5;
    const int choff = (ky * 64 + kx) * 64 + (c & 1) * 32;  // scalar-uniform

    __syncthreads();
#pragma unroll
    for (int p = 0; p < 2; ++p) {          // wff: 128 oc-rows x 32 k
      int m = p * 64 + mrow;
      *(int4*)(&Bs[m * LDC + qt * 8]) =
          *(const int4*)(wff + (oc0 + m) * 1600 + k0 + qt * 8);
    }
#pragma unroll
    for (int p = 0; p < 2; ++p) {          // x-tile: contiguous bf16 (NHWC)
      int m = p * 64 + mrow;
      *(int4*)(&As[m * LDC + qt * 8]) = *(const int4*)(xt + xbase[p] + choff);
    }
    __syncthreads();

    short8 xf[4], wf[4];
#pragma unroll
    for (int j = 0; j < 4; j++)
      xf[j] = *(const short8*)(&As[(wn * 64 + j * 16 + r) * LDC + q * 8]);
#pragma unroll
    for (int i = 0; i < 4; i++)
      wf[i] = *(const short8*)(&Bs[(woc * 64 + i * 16 + r) * LDC + q * 8]);
#pragma unroll
    for (int i = 0; i < 4; i++)
#pragma unroll
      for (int j = 0; j < 4; j++)
        acc[i][j] = __builtin_amdgcn_mfma_f32_16x16x32_bf16(wf[i], xf[j],
                                                            acc[i][j], 0, 0, 0);
  }

  // epilogue: FL layout. oc = oc0+woc*64+ic*16+q*4+d -> w_fl = by*4+woc*2+
  // (ic>>1), i_fl = ic&1. Pair ic={2p,2p+1} into one int4 (8 shorts).
  // n = n0+wn*64+j*16+r -> tile = bx*2+wn. Store addr = tile*16384 + j*4096
  // + (w_fl*64 + q*16 + r)*8 : lane-contiguous -> 512 B/instr coalesced.
  const int tile = blockIdx.x * 2 + wn;
#pragma unroll
  for (int j = 0; j < 4; j++) {
#pragma unroll
    for (int p = 0; p < 2; p++) {
      const int w_fl = blockIdx.y * 4 + woc * 2 + p;
      alignas(16) unsigned short up[8];
#pragma unroll
      for (int d = 0; d < 4; ++d) up[d] = f2h(acc[2 * p][j][d]);
#pragma unroll
      for (int d = 0; d < 4; ++d) up[4 + d] = f2h(acc[2 * p + 1][j][d]);
      *(int4*)(&u0_fl[tile * 16384 + j * 4096 + (w_fl * 64 + q * 16 + r) * 8]) =
          *(const int4*)up;
    }
  }
}

// ---------------------------------------------------------------------------
// 8-wave GEMM accumulate: acc = W_rec @ a, C-layout. Wave w owns oc rows
// [32w, 32w+32). No LDS writeback, no barriers (caller manages).
__device__ __forceinline__ void gemm_acc8(const short* a_lds,
                                          const unsigned short* __restrict__
                                              wrec_sw,
                                          int w, int q, int r,
                                          f32x4 acc[2][4]) {
#pragma unroll
  for (int i = 0; i < 2; i++)
#pragma unroll
    for (int j = 0; j < 4; j++) acc[i][j] = (f32x4){0.f, 0.f, 0.f, 0.f};

#pragma unroll
  for (int c = 0; c < 8; ++c) {
    short8 afr[2], bfr[4];
#pragma unroll
    for (int i = 0; i < 2; i++)
      afr[i] = *(const short8*)(wrec_sw +
               (((c * 4 + q) << 8) + w * 32 + i * 16 + r) * 8);
#pragma unroll
    for (int j = 0; j < 4; j++)
      bfr[j] = *(const short8*)(&a_lds[(j * 16 + r) * LDA + c * 32 + q * 8]);
#pragma unroll
    for (int i = 0; i < 2; i++)
#pragma unroll
      for (int j = 0; j < 4; j++)
        acc[i][j] = __builtin_amdgcn_mfma_f32_16x16x32_bf16(afr[i], bfr[j],
                                                            acc[i][j], 0, 0, 0);
  }
}

// ---------------------------------------------------------------------------
// Paired iteration, 512 threads / 8 waves, grid 1800 (64 n each). All u
// buffers FL: thread t accesses int4 at blockIdx*16384 + j*4096 + t*8,
// holding (n = n0+j*16+r, oc = w*32 + i*16 + q*4 + d), i = int4 half.
// acc[i][j][d] in C-layout matches exactly. rec stays fp32.
template <int FIRST>
__global__ __launch_bounds__(512, 4) void iter_pair(
    const unsigned short* __restrict__ wrec_sw,
    const unsigned short* __restrict__ u0, const float* __restrict__ thr,
    const unsigned short* __restrict__ uin,      // prev even state (uB)
    unsigned short* __restrict__ uA, unsigned short* __restrict__ uB,
    float* __restrict__ norms, int* __restrict__ flag, int itA) {
  __shared__ short a_lds[64 * LDA];
  __shared__ float red[32];

  const int t = threadIdx.x;
  if (!FIRST) {
    if (*(volatile int*)flag) return;            // converged earlier
    float dA = 0.f, nA = 0.f, dB = 0.f, nB = 0.f;
#pragma unroll
    for (int s = 0; s < 8; ++s) {
      dA += norms[(itA - 2) * 16 + s];
      nA += norms[(itA - 2) * 16 + 8 + s];
      dB += norms[(itA - 1) * 16 + s];
      nB += norms[(itA - 1) * 16 + 8 + s];
    }
    if (dA < 1e-6f * nA || dB < 1e-6f * nB) {    // fro ratio < 1e-3
      if (t == 0) *flag = 1;
      return;
    }
  }

  const int lane = t & 63, w = t >> 6;     // w in 0..7
  const int q = lane >> 4, r = lane & 15;
  const unsigned base = blockIdx.x * 16384 + t * 8;   // + j*4096

  float thc[2][4];
#pragma unroll
  for (int i = 0; i < 2; ++i) {
    float4 th = *(const float4*)(thr + w * 32 + i * 16 + q * 4);
    thc[i][0] = th.x; thc[i][1] = th.y; thc[i][2] = th.z; thc[i][3] = th.w;
  }

  int4 sv[4], u0c[4];                      // j-indexed, 8 fp16 each
#pragma unroll
  for (int j = 0; j < 4; ++j) {
    u0c[j] = *(const int4*)(u0 + base + j * 4096);
    sv[j] = FIRST ? u0c[j] : *(const int4*)(uin + base + j * 4096);
  }

  // ---- a0 = relu(sv - thr) -> LDS ----
#pragma unroll
  for (int j = 0; j < 4; ++j) {
    const unsigned short* hs = (const unsigned short*)&sv[j];
#pragma unroll
    for (int i = 0; i < 2; ++i) {
      alignas(8) unsigned short ap[4];
#pragma unroll
      for (int d = 0; d < 4; ++d) {
        float a = h2f(hs[i * 4 + d]) - thc[i][d];
        ap[d] = f2bf(a > 0.f ? a : 0.f);
      }
      *(uint2*)(&a_lds[(j * 16 + r) * LDA + w * 32 + i * 16 + q * 4]) =
          *(const uint2*)ap;
    }
  }
  __syncthreads();

  // ---- iteration A: GEMM + in-register update ----
  f32x4 acc[2][4];
  gemm_acc8(a_lds, wrec_sw, w, q, r, acc);

  float d2A = 0.f, n2A = 0.f;
#pragma unroll
  for (int j = 0; j < 4; ++j) {
    const unsigned short* us = (const unsigned short*)&u0c[j];
    const unsigned short* hs = (const unsigned short*)&sv[j];
    alignas(16) unsigned short up[8];
#pragma unroll
    for (int i = 0; i < 2; ++i)
#pragma unroll
      for (int d = 0; d < 4; ++d) {
        float uo = FIRST ? 0.f : h2f(hs[i * 4 + d]);
        float un = 0.5f * uo + 0.5f * (h2f(us[i * 4 + d]) - acc[i][j][d]);
        float df = un - uo;
        d2A += df * df;
        n2A += un * un;
        up[i * 4 + d] = f2h(un);
      }
    sv[j] = *(const int4*)up;
    *(int4*)(uA + base + j * 4096) = sv[j];  // coalesced; hides under GEMM B
  }
  __syncthreads();                         // all GEMM-A a_lds reads complete

  // ---- aA = relu(sv - thr) -> LDS (recomputed from rounded sv) ----
#pragma unroll
  for (int j = 0; j < 4; ++j) {
    const unsigned short* hs = (const unsigned short*)&sv[j];
#pragma unroll
    for (int i = 0; i < 2; ++i) {
      alignas(8) unsigned short ap[4];
#pragma unroll
      for (int d = 0; d < 4; ++d) {
        float a = h2f(hs[i * 4 + d]) - thc[i][d];
        ap[d] = f2bf(a > 0.f ? a : 0.f);
      }
      *(uint2*)(&a_lds[(j * 16 + r) * LDA + w * 32 + i * 16 + q * 4]) =
          *(const uint2*)ap;
    }
  }
  __syncthreads();

  // ---- iteration B: GEMM + in-register update ----
  gemm_acc8(a_lds, wrec_sw, w, q, r, acc);

  float d2B = 0.f, n2B = 0.f;
#pragma unroll
  for (int j = 0; j < 4; ++j) {
    const unsigned short* us = (const unsigned short*)&u0c[j];
    const unsigned short* hs = (const unsigned short*)&sv[j];
    alignas(16) unsigned short up[8];
#pragma unroll
    for (int i = 0; i < 2; ++i)
#pragma unroll
      for (int d = 0; d < 4; ++d) {
        float uo = h2f(hs[i * 4 + d]);
        float un = 0.5f * uo + 0.5f * (h2f(us[i * 4 + d]) - acc[i][j][d]);
        float df = un - uo;
        d2B += df * df;
        n2B += un * un;
        up[i * 4 + d] = f2h(un);
      }
    *(int4*)(uB + base + j * 4096) = *(const int4*)up;
  }

  // ---- reduction: wave -> block -> 8-slot atomics ----
#pragma unroll
  for (int off = 32; off; off >>= 1) {
    d2A += __shfl_down(d2A, off, 64);
    n2A += __shfl_down(n2A, off, 64);
    d2B += __shfl_down(d2B, off, 64);
    n2B += __shfl_down(n2B, off, 64);
  }
  if (lane == 0) {
    red[w] = d2A; red[8 + w] = n2A; red[16 + w] = d2B; red[24 + w] = n2B;
  }
  __syncthreads();
  if (t == 0) {
    float a0 = 0.f, a1 = 0.f, a2 = 0.f, a3 = 0.f;
#pragma unroll
    for (int s = 0; s < 8; ++s) {
      a0 += red[s]; a1 += red[8 + s]; a2 += red[16 + s]; a3 += red[24 + s];
    }
    const int slot = blockIdx.x & 7;
    atomicAdd(&norms[itA * 16 + slot], a0);
    atomicAdd(&norms[itA * 16 + 8 + slot], a1);
    atomicAdd(&norms[(itA + 1) * 16 + slot], a2);
    atomicAdd(&norms[(itA + 1) * 16 + 8 + slot], a3);
  }
}

// ---------------------------------------------------------------------------
// Single iteration it: uin -> uout, FL layout (512 threads / 8 waves). Used
// for it=41 (pair path) and the fallback chain.
template <int FIRST>
__global__ __launch_bounds__(512, 4) void iter_one(
    const unsigned short* __restrict__ wrec_sw,
    const unsigned short* __restrict__ u0, const float* __restrict__ thr,
    const unsigned short* __restrict__ uin, unsigned short* __restrict__ uout,
    float* __restrict__ norms, int* __restrict__ flag, int it) {
  __shared__ short a_lds[64 * LDA];
  __shared__ float red[16];

  const int t = threadIdx.x;
  if (!FIRST) {
    if (*(volatile int*)flag) return;
    float dA = 0.f, nA = 0.f, dB = 0.f, nB = 0.f;
#pragma unroll
    for (int s = 0; s < 8; ++s) {
      dA += norms[(it - 2) * 16 + s];
      nA += norms[(it - 2) * 16 + 8 + s];
      dB += norms[(it - 1) * 16 + s];
      nB += norms[(it - 1) * 16 + 8 + s];
    }
    if (dA < 1e-6f * nA || dB < 1e-6f * nB) {
      if (t == 0) *flag = 1;
      return;
    }
  }

  const int lane = t & 63, w = t >> 6;
  const int q = lane >> 4, r = lane & 15;
  const unsigned base = blockIdx.x * 16384 + t * 8;

  float thc[2][4];
#pragma unroll
  for (int i = 0; i < 2; ++i) {
    float4 th = *(const float4*)(thr + w * 32 + i * 16 + q * 4);
    thc[i][0] = th.x; thc[i][1] = th.y; thc[i][2] = th.z; thc[i][3] = th.w;
  }

  int4 sv[4], u0c[4];
#pragma unroll
  for (int j = 0; j < 4; ++j) {
    u0c[j] = *(const int4*)(u0 + base + j * 4096);
    sv[j] = FIRST ? u0c[j] : *(const int4*)(uin + base + j * 4096);
  }

#pragma unroll
  for (int j = 0; j < 4; ++j) {
    const unsigned short* hs = (const unsigned short*)&sv[j];
#pragma unroll
    for (int i = 0; i < 2; ++i) {
      alignas(8) unsigned short ap[4];
#pragma unroll
      for (int d = 0; d < 4; ++d) {
        float a = h2f(hs[i * 4 + d]) - thc[i][d];
        ap[d] = f2bf(a > 0.f ? a : 0.f);
      }
      *(uint2*)(&a_lds[(j * 16 + r) * LDA + w * 32 + i * 16 + q * 4]) =
          *(const uint2*)ap;
    }
  }
  __syncthreads();

  f32x4 acc[2][4];
  gemm_acc8(a_lds, wrec_sw, w, q, r, acc);

  float d2 = 0.f, n2 = 0.f;
#pragma unroll
  for (int j = 0; j < 4; ++j) {
    const unsigned short* us = (const unsigned short*)&u0c[j];
    const unsigned short* hs = (const unsigned short*)&sv[j];
    alignas(16) unsigned short up[8];
#pragma unroll
    for (int i = 0; i < 2; ++i)
#pragma unroll
      for (int d = 0; d < 4; ++d) {
        float uo = FIRST ? 0.f : h2f(hs[i * 4 + d]);
        float un = 0.5f * uo + 0.5f * (h2f(us[i * 4 + d]) - acc[i][j][d]);
        float df = un - uo;
        d2 += df * df;
        n2 += un * un;
        up[i * 4 + d] = f2h(un);
      }
    *(int4*)(uout + base + j * 4096) = *(const int4*)up;
  }

#pragma unroll
  for (int off = 32; off; off >>= 1) {
    d2 += __shfl_down(d2, off, 64);
    n2 += __shfl_down(n2, off, 64);
  }
  if (lane == 0) { red[w] = d2; red[8 + w] = n2; }
  __syncthreads();
  if (t == 0) {
    float a0 = 0.f, a1 = 0.f;
#pragma unroll
    for (int s = 0; s < 8; ++s) { a0 += red[s]; a1 += red[8 + s]; }
    const int slot = blockIdx.x & 7;
    atomicAdd(&norms[it * 16 + slot], a0);
    atomicAdd(&norms[it * 16 + 8 + slot], a1);
  }
}

// ---------------------------------------------------------------------------
// sel: first it in [1,41] with d2 < 1e-6*n2 (else 41); odd -> uA (sel=0),
// even -> uB (sel=1).
__global__ void sel_kernel(const float* __restrict__ norms,
                           int* __restrict__ sel) {
  int it = 1;
  for (; it <= 41; ++it) {
    float d = 0.f, n = 0.f;
    for (int s = 0; s < 8; ++s) {
      d += norms[it * 16 + s];
      n += norms[it * 16 + 8 + s];
    }
    if (d < 1e-6f * n) break;
  }
  if (it > 41) it = 41;
  *sel = (it & 1) ? 0 : 1;
}
__global__ void set_sel(int* __restrict__ sel, int v) { *sel = v; }

// ---------------------------------------------------------------------------
// Final: out(NCHW fp32) = relu(u - thr), u in FL layout. Block = one tile
// (64 n), 512 threads; thread t reads 4 coalesced int4 and scatters fp32.
__global__ __launch_bounds__(512) void final_out(
    const unsigned short* __restrict__ uA,
    const unsigned short* __restrict__ uB, const int* __restrict__ sel,
    const float* __restrict__ thr, float* __restrict__ out) {
  const unsigned short* u = (*sel) ? uB : uA;
  const int t = threadIdx.x;
  const int lane = t & 63, w = t >> 6;
  const int q = lane >> 4, r = lane & 15;
  const unsigned base = blockIdx.x * 16384 + t * 8;

  float thc[2][4];
#pragma unroll
  for (int i = 0; i < 2; ++i) {
    float4 th = *(const float4*)(thr + w * 32 + i * 16 + q * 4);
    thc[i][0] = th.x; thc[i][1] = th.y; thc[i][2] = th.z; thc[i][3] = th.w;
  }

#pragma unroll
  for (int j = 0; j < 4; ++j) {
    int4 raw = *(const int4*)(u + base + j * 4096);
    const unsigned short* rs = (const unsigned short*)&raw;
    const int n = blockIdx.x * 64 + j * 16 + r;
    const int b = n / 3600, s = n - b * 3600;
    float* ob = out + (long)b * 921600 + s;
#pragma unroll
    for (int i = 0; i < 2; ++i)
#pragma unroll
      for (int d = 0; d < 4; ++d) {
        const int oc = w * 32 + i * 16 + q * 4 + d;
        float v = h2f(rs[i * 4 + d]) - thc[i][d];
        ob[oc * 3600] = v > 0.f ? v : 0.f;
      }
  }
}

// ---------------------------------------------------------------------------
extern "C" void kernel_launch(void* const* d_in, const int* in_sizes, int n_in,
                              void* d_out, int out_size, void* d_ws,
                              size_t ws_size, hipStream_t stream) {
  const float* x      = (const float*)d_in[0];
  const float* wff_f  = (const float*)d_in[1];
  const float* wrec_f = (const float*)d_in[2];
  const float* thr    = (const float*)d_in[3];
  float* out = (float*)d_out;

  char* ws = (char*)d_ws;
  int* flag = (int*)ws;                                      // [0,4)
  int* sel  = (int*)(ws + 8);                                // [8,12)
  float* norms = (float*)(ws + 64);                          // 42*16*4 = 2688 B
  unsigned short* wff     = (unsigned short*)(ws + 4096);      // 819200 B
  unsigned short* wrec_sw = (unsigned short*)(ws + 823296);    // 131072 B
  // xt (16.8 MB) aliases the head of uB (59 MB): xt dies after conv; uB is
  // first written in iteration B of the first pair launch.
  unsigned short* xt = (unsigned short*)(ws + 983040);
  unsigned short* uB = (unsigned short*)(ws + 983040);         // 58982400 B
  unsigned short* u0 = (unsigned short*)(ws + 59965440);       // 58982400 B
  unsigned short* uA = (unsigned short*)(ws + 118947840);      // 58982400 B
  const size_t NEEDED = 118947840ULL + 58982400ULL;            // ~178 MB

  hipMemsetAsync(d_ws, 0, 4096, stream);  // flag + sel + norm slots
  cast_weights<<<1856, 256, 0, stream>>>(wff_f, wrec_f, wff, wrec_sw);
  transpose_x<<<512, 256, 0, stream>>>(x, xt);
  conv_kernel<<<dim3(900, 2), 256, 0, stream>>>(xt, wff, u0);

  if (ws_size >= NEEDED) {
    // paired path: (1,2), (3,4), ..., (39,40), then single 41 -> 41 bodies
    iter_pair<1><<<1800, 512, 0, stream>>>(wrec_sw, u0, thr, uB, uA, uB,
                                           norms, flag, 1);
    for (int itA = 3; itA <= 39; itA += 2)
      iter_pair<0><<<1800, 512, 0, stream>>>(wrec_sw, u0, thr, uB, uA, uB,
                                             norms, flag, itA);
    iter_one<0><<<1800, 512, 0, stream>>>(wrec_sw, u0, thr, uB, uA, norms,
                                          flag, 41);
    sel_kernel<<<1, 1, 0, stream>>>(norms, sel);
  } else {
    // fallback: proven single-step chain in uB
    iter_one<1><<<1800, 512, 0, stream>>>(wrec_sw, u0, thr, uB, uB, norms,
                                          flag, 1);
    for (int it = 2; it <= 41; ++it)
      iter_one<0><<<1800, 512, 0, stream>>>(wrec_sw, u0, thr, uB, uB, norms,
                                            flag, it);
    set_sel<<<1, 1, 0, stream>>>(sel, 1);
  }
  final_out<<<1800, 512, 0, stream>>>(uA, uB, sel, thr, out);
}